// Round 8
// baseline (1318.242 us; speedup 1.0000x reference)
//
#include <hip/hip_runtime.h>

#define BB 64
#define TT 2048
#define II 64
#define HH 256
#define NTHR 256

typedef _Float16 v8h __attribute__((ext_vector_type(8)));
typedef float v4f __attribute__((ext_vector_type(4)));
typedef int v4i __attribute__((ext_vector_type(4)));

#define PK(a, b) __builtin_bit_cast(int, __builtin_amdgcn_cvt_pkrtz((a), (b)))
#define MFMA __builtin_amdgcn_mfma_f32_16x16x32_f16

// tanh(x) = 1 - 2/(e^{2x}+1); v_exp + v_rcp, correct limits at +-inf.
__device__ __forceinline__ float ftanh(float x) {
    float e = __expf(2.0f * x);
    return 1.0f - 2.0f * __builtin_amdgcn_rcpf(e + 1.0f);
}

// DPP ctrl: 0xB1 quad ^1, 0x4E quad ^2, 0x141 ROW_HALF_MIRROR (eff ^4 after
// ^1,^2), 0x140 ROW_MIRROR (eff ^8). 16-lane-row scoped -> lane 0 of each
// row ends with the row sum. (Harness-verified R6/R7.)
template <int CTRL>
__device__ __forceinline__ float dpp_add(float v) {
    int s = __builtin_amdgcn_update_dpp(0, __float_as_int(v), CTRL, 0xF, 0xF, true);
    return v + __int_as_float(s);
}

__device__ __forceinline__ v8h xfrag(const float4 s0, const float4 s1) {
    v4i r = {PK(s0.x, s0.y), PK(s0.z, s0.w), PK(s1.x, s1.y), PK(s1.z, s1.w)};
    return __builtin_bit_cast(v8h, r);
}

// R8: kill the hidden operand-marshalling tax. R7 counters: VGPR_Count 152
// < 160 pinned ints (weights NOT register-resident) and VALUBusy ~460cy/step
// vs ~150cy of visible VALU work -> ~40 MFMAs x 4 v_mov quad-assembly + L2
// reloads of evicted fragments were serialized ahead of the MFMAs every step.
// Fix: B-fragments are first-class v8h (128-bit) values pinned AS VECTORS
// (asm "+v" on v8h allocates a VReg_128 quad, cannot be rematerialized);
// bias quads + zero quad likewise pinned so MFMA C-operands are read in
// place. MFMA then consumes everything with ZERO per-step moves.
// Also: accumulate split into 3 chains (depth 4/3/3, was 6+4) to cut
// dependent-MFMA latency. Everything else = R7 (passed, conflicts 0).
__launch_bounds__(NTHR, 1)
__global__ void rnn_fused(const float* __restrict__ x,
                          const float* __restrict__ W_ih,
                          const float* __restrict__ W_hh,
                          const float* __restrict__ b_ih,
                          const float* __restrict__ b_hh,
                          const float* __restrict__ W_fc,
                          const float* __restrict__ b_fc,
                          float* __restrict__ out) {
    __shared__ __align__(16) __fp16 hlds[2][HH];  // 1 KB, double-buffered
    __shared__ float part[TT + 1][4];             // head partials, 32.8 KB

    const int tid  = threadIdx.x;
    const int b    = blockIdx.x;
    const int lane = tid & 63;
    const int w    = tid >> 6;     // wave 0..3: output cols [64w, 64w+64)
    const int g    = lane >> 4;    // 16-lane group 0..3 (k sub-slice)
    const int c16  = lane & 15;

    // ---- B fragments: bf[tc][T]: lane (g,c16) holds
    // W[n = 64w+16tc+c16][k = 32T + 8g + j], j=0..7  (T=8,9 -> W_ih, k-256)
    v8h bf[4][10];   // 160 VGPRs as 40 aligned quads
    v4f bvv[4];      // bias splat quads (C-operand, read in place)
    float wf[4];
#pragma unroll
    for (int tc = 0; tc < 4; ++tc) {
        const int n = 64 * w + 16 * tc + c16;
#pragma unroll
        for (int T = 0; T < 8; ++T) {
            const float* wp = W_hh + n * HH + 32 * T + 8 * g;
            const float4 f0 = *(const float4*)wp;
            const float4 f1 = *(const float4*)(wp + 4);
            v4i r = {PK(f0.x, f0.y), PK(f0.z, f0.w), PK(f1.x, f1.y), PK(f1.z, f1.w)};
            bf[tc][T] = __builtin_bit_cast(v8h, r);
        }
#pragma unroll
        for (int T = 8; T < 10; ++T) {
            const float* wp = W_ih + n * II + 32 * (T - 8) + 8 * g;
            const float4 f0 = *(const float4*)wp;
            const float4 f1 = *(const float4*)(wp + 4);
            v4i r = {PK(f0.x, f0.y), PK(f0.z, f0.w), PK(f1.x, f1.y), PK(f1.z, f1.w)};
            bf[tc][T] = __builtin_bit_cast(v8h, r);
        }
        const float bias = b_ih[n] + b_hh[n];
        bvv[tc] = (v4f){bias, bias, bias, bias};
        wf[tc] = W_fc[n];
    }
    v4f zq = (v4f){0.f, 0.f, 0.f, 0.f};  // zero C-quad for chains B/C
    // pin AS VECTORS: each v8h/v4f lives in one aligned VGPR tuple for the
    // whole kernel; cannot be rematerialized/split (R7 lesson: scalar pins
    // did not keep values resident -> per-step quad re-assembly + reloads)
#pragma unroll
    for (int tc = 0; tc < 4; ++tc) {
#pragma unroll
        for (int T = 0; T < 10; ++T) asm volatile("" : "+v"(bf[tc][T]));
        asm volatile("" : "+v"(bvv[tc]));
        asm volatile("" : "+v"(wf[tc]));
    }
    asm volatile("" : "+v"(zq));
    const float bfc = b_fc[0];

    for (int idx = tid; idx < 2 * HH; idx += NTHR)
        ((__fp16*)hlds)[idx] = (__fp16)0;  // h_0 = 0
    __syncthreads();

    const float* xrow = x + (size_t)b * TT * II;
    float* outb = out + (size_t)b * TT;

    // h read base: GROUP-UNIFORM chunk address (broadcast within group);
    // k-tile T at byte offset T*64. Only lanes c16==0 feed D-row 0.
    const char* hrd0 = (const char*)&hlds[0][0] + g * 16;
    const char* hrd1 = (const char*)&hlds[1][0] + g * 16;
    // h write (lanes 0-15 only): col = 64w + 16tc + c16, tc -> +16 halves
    __fp16* hwr0 = &hlds[0][64 * w + c16];
    __fp16* hwr1 = &hlds[1][64 * w + c16];

    // x pipeline: xf8/xf9 = frags for step i; slots A/B raw rows i+1, i+2
    v8h xf8, xf9;
    float4 rA0, rA1, rA2, rA3, rB0, rB1, rB2, rB3;
    {
        const float* x0 = xrow;
        xf8 = xfrag(*(const float4*)(x0 + 8 * g), *(const float4*)(x0 + 8 * g + 4));
        xf9 = xfrag(*(const float4*)(x0 + 32 + 8 * g), *(const float4*)(x0 + 36 + 8 * g));
        const float* x1 = xrow + II;
        rA0 = *(const float4*)(x1 + 8 * g);      rA1 = *(const float4*)(x1 + 8 * g + 4);
        rA2 = *(const float4*)(x1 + 32 + 8 * g); rA3 = *(const float4*)(x1 + 36 + 8 * g);
        const float* x2 = xrow + 2 * II;
        rB0 = *(const float4*)(x2 + 8 * g);      rB1 = *(const float4*)(x2 + 8 * g + 4);
        rB2 = *(const float4*)(x2 + 32 + 8 * g); rB3 = *(const float4*)(x2 + 36 + 8 * g);
    }

    float ph = 0.0f;  // per-lane head partial of previous step (pre-reduce)

#define STEP(I, P, R0, R1, R2, R3)                                             \
    {                                                                          \
        /* issue all 8 h-tile reads (conflict-free b128 broadcast) */          \
        const char* hrd = (P) ? hrd1 : hrd0;                                   \
        const v8h hv0 = *(const v8h*)(hrd + 0 * 64);                           \
        const v8h hv1 = *(const v8h*)(hrd + 1 * 64);                           \
        const v8h hv2 = *(const v8h*)(hrd + 2 * 64);                           \
        const v8h hv3 = *(const v8h*)(hrd + 3 * 64);                           \
        const v8h hv4 = *(const v8h*)(hrd + 4 * 64);                           \
        const v8h hv5 = *(const v8h*)(hrd + 5 * 64);                           \
        const v8h hv6 = *(const v8h*)(hrd + 6 * 64);                           \
        const v8h hv7 = *(const v8h*)(hrd + 7 * 64);                           \
        /* deferred head of step I-1: 16-lane DPP reduce, fills read latency */\
        if ((I) > 0) {                                                         \
            float hc = ph;                                                     \
            hc = dpp_add<0xB1>(hc);                                            \
            hc = dpp_add<0x4E>(hc);                                            \
            hc = dpp_add<0x141>(hc);                                           \
            hc = dpp_add<0x140>(hc);                                           \
            if (lane == 0) part[I][w] = hc;                                    \
        }                                                                      \
        /* chain A: bias + x tiles (8,9) + h tiles 0,1  (depth 4) */           \
        v4f aA0 = MFMA(xf8, bf[0][8], bvv[0], 0, 0, 0);                        \
        v4f aA1 = MFMA(xf8, bf[1][8], bvv[1], 0, 0, 0);                        \
        v4f aA2 = MFMA(xf8, bf[2][8], bvv[2], 0, 0, 0);                        \
        v4f aA3 = MFMA(xf8, bf[3][8], bvv[3], 0, 0, 0);                        \
        aA0 = MFMA(xf9, bf[0][9], aA0, 0, 0, 0);                               \
        aA1 = MFMA(xf9, bf[1][9], aA1, 0, 0, 0);                               \
        aA2 = MFMA(xf9, bf[2][9], aA2, 0, 0, 0);                               \
        aA3 = MFMA(xf9, bf[3][9], aA3, 0, 0, 0);                               \
        aA0 = MFMA(hv0, bf[0][0], aA0, 0, 0, 0);                               \
        aA1 = MFMA(hv0, bf[1][0], aA1, 0, 0, 0);                               \
        aA2 = MFMA(hv0, bf[2][0], aA2, 0, 0, 0);                               \
        aA3 = MFMA(hv0, bf[3][0], aA3, 0, 0, 0);                               \
        aA0 = MFMA(hv1, bf[0][1], aA0, 0, 0, 0);                               \
        aA1 = MFMA(hv1, bf[1][1], aA1, 0, 0, 0);                               \
        aA2 = MFMA(hv1, bf[2][1], aA2, 0, 0, 0);                               \
        aA3 = MFMA(hv1, bf[3][1], aA3, 0, 0, 0);                               \
        /* chain B: h tiles 2,3,4 from pinned zero quad  (depth 3) */          \
        v4f aB0 = MFMA(hv2, bf[0][2], zq, 0, 0, 0);                            \
        v4f aB1 = MFMA(hv2, bf[1][2], zq, 0, 0, 0);                            \
        v4f aB2 = MFMA(hv2, bf[2][2], zq, 0, 0, 0);                            \
        v4f aB3 = MFMA(hv2, bf[3][2], zq, 0, 0, 0);                            \
        aB0 = MFMA(hv3, bf[0][3], aB0, 0, 0, 0);                               \
        aB1 = MFMA(hv3, bf[1][3], aB1, 0, 0, 0);                               \
        aB2 = MFMA(hv3, bf[2][3], aB2, 0, 0, 0);                               \
        aB3 = MFMA(hv3, bf[3][3], aB3, 0, 0, 0);                               \
        aB0 = MFMA(hv4, bf[0][4], aB0, 0, 0, 0);                               \
        aB1 = MFMA(hv4, bf[1][4], aB1, 0, 0, 0);                               \
        aB2 = MFMA(hv4, bf[2][4], aB2, 0, 0, 0);                               \
        aB3 = MFMA(hv4, bf[3][4], aB3, 0, 0, 0);                               \
        /* chain C: h tiles 5,6,7 from pinned zero quad  (depth 3) */          \
        v4f aC0 = MFMA(hv5, bf[0][5], zq, 0, 0, 0);                            \
        v4f aC1 = MFMA(hv5, bf[1][5], zq, 0, 0, 0);                            \
        v4f aC2 = MFMA(hv5, bf[2][5], zq, 0, 0, 0);                            \
        v4f aC3 = MFMA(hv5, bf[3][5], zq, 0, 0, 0);                            \
        aC0 = MFMA(hv6, bf[0][6], aC0, 0, 0, 0);                               \
        aC1 = MFMA(hv6, bf[1][6], aC1, 0, 0, 0);                               \
        aC2 = MFMA(hv6, bf[2][6], aC2, 0, 0, 0);                               \
        aC3 = MFMA(hv6, bf[3][6], aC3, 0, 0, 0);                               \
        aC0 = MFMA(hv7, bf[0][7], aC0, 0, 0, 0);                               \
        aC1 = MFMA(hv7, bf[1][7], aC1, 0, 0, 0);                               \
        aC2 = MFMA(hv7, bf[2][7], aC2, 0, 0, 0);                               \
        aC3 = MFMA(hv7, bf[3][7], aC3, 0, 0, 0);                               \
        /* x pipeline rotate: consume slot (row I+1), refill with row I+3 */   \
        xf8 = xfrag(R0, R1);                                                   \
        xf9 = xfrag(R2, R3);                                                   \
        {                                                                      \
            const int rn = ((I) + 3 < TT) ? ((I) + 3) : (TT - 1);              \
            const float* xp = xrow + rn * II;                                  \
            R0 = *(const float4*)(xp + 8 * g);                                 \
            R1 = *(const float4*)(xp + 8 * g + 4);                             \
            R2 = *(const float4*)(xp + 32 + 8 * g);                            \
            R3 = *(const float4*)(xp + 36 + 8 * g);                            \
        }                                                                      \
        /* tanh on D-row 0 (valid on lanes g==0; bounded garbage elsewhere) */ \
        const float h0 = ftanh(aA0[0] + aB0[0] + aC0[0]);                      \
        const float h1 = ftanh(aA1[0] + aB1[0] + aC1[0]);                      \
        const float h2 = ftanh(aA2[0] + aB2[0] + aC2[0]);                      \
        const float h3 = ftanh(aA3[0] + aB3[0] + aC3[0]);                      \
        ph = fmaf(h3, wf[3], fmaf(h2, wf[2], fmaf(h1, wf[1], h0 * wf[0])));    \
        if (lane < 16) {                                                       \
            __fp16* hp = (P) ? hwr0 : hwr1;                                    \
            hp[0]  = (__fp16)h0;                                               \
            hp[16] = (__fp16)h1;                                               \
            hp[32] = (__fp16)h2;                                               \
            hp[48] = (__fp16)h3;                                               \
        }                                                                      \
        /* LDS-only barrier: vmcnt NOT drained (x prefetch spans steps) */     \
        asm volatile("s_waitcnt lgkmcnt(0)\n\ts_barrier" ::: "memory");        \
    }

    for (int ib = 0; ib < TT; ib += 2) {
        STEP(ib, 0, rA0, rA1, rA2, rA3)
        STEP(ib + 1, 1, rB0, rB1, rB2, rB3)
    }
#undef STEP

    // final head (step TT-1) -> part[TT]
    {
        float hc = ph;
        hc = dpp_add<0xB1>(hc);
        hc = dpp_add<0x4E>(hc);
        hc = dpp_add<0x141>(hc);
        hc = dpp_add<0x140>(hc);
        if (lane == 0) part[TT][w] = hc;
    }
    __syncthreads();

    // ---- deferred output head: out[b][i] = sum(part[i+1][0..3]) + bfc ----
    for (int i = tid; i < TT; i += NTHR) {
        const float4 s = *(const float4*)&part[i + 1][0];
        outb[i] = s.x + s.y + s.z + s.w + bfc;
    }
}

extern "C" void kernel_launch(void* const* d_in, const int* in_sizes, int n_in,
                              void* d_out, int out_size, void* d_ws, size_t ws_size,
                              hipStream_t stream) {
    const float* x    = (const float*)d_in[0];
    const float* W_ih = (const float*)d_in[1];
    const float* W_hh = (const float*)d_in[2];
    const float* b_ih = (const float*)d_in[3];
    const float* b_hh = (const float*)d_in[4];
    const float* W_fc = (const float*)d_in[5];
    const float* b_fc = (const float*)d_in[6];
    float* out = (float*)d_out;

    rnn_fused<<<BB, NTHR, 0, stream>>>(x, W_ih, W_hh, b_ih, b_hh, W_fc, b_fc, out);
}

// Round 9
// 1170.781 us; speedup vs baseline: 1.1260x; 1.1260x over previous
//
#include <hip/hip_runtime.h>

#define BB 64
#define TT 2048
#define II 64
#define HH 256
#define NTHR 512   // 8 waves x 32 output cols; 2 waves/SIMD

typedef _Float16 v8h __attribute__((ext_vector_type(8)));
typedef float v4f __attribute__((ext_vector_type(4)));
typedef int v4i __attribute__((ext_vector_type(4)));

#define PK(a, b) __builtin_bit_cast(int, __builtin_amdgcn_cvt_pkrtz((a), (b)))
#define MFMA __builtin_amdgcn_mfma_f32_16x16x32_f16

// tanh(x) = 1 - 2/(e^{2x}+1); v_exp + v_rcp, correct limits at +-inf.
__device__ __forceinline__ float ftanh(float x) {
    float e = __expf(2.0f * x);
    return 1.0f - 2.0f * __builtin_amdgcn_rcpf(e + 1.0f);
}

// DPP ctrl: 0xB1 quad ^1, 0x4E quad ^2, 0x141 ROW_HALF_MIRROR (eff ^4 after
// ^1,^2), 0x140 ROW_MIRROR (eff ^8). 16-lane-row scoped -> lane 0 of each
// row ends with the row sum. (Harness-verified R6-R8.)
template <int CTRL>
__device__ __forceinline__ float dpp_add(float v) {
    int s = __builtin_amdgcn_update_dpp(0, __float_as_int(v), CTRL, 0xF, 0xF, true);
    return v + __int_as_float(s);
}

__device__ __forceinline__ v8h xfrag(const float4 s0, const float4 s1) {
    v4i r = {PK(s0.x, s0.y), PK(s0.z, s0.w), PK(s1.x, s1.y), PK(s1.z, s1.w)};
    return __builtin_bit_cast(v8h, r);
}

// R9: fit the working set in the 256-arch-VGPR encoding limit. R8 counters:
// VGPR_Count=160 == exactly the pinned bf size; the other ~140 live values
// (acc/hv/x-pipe/temps) were shuffled through AGPR copies -> the ~400cy/step
// hidden VALU tax (8.7% VALUBusy vs ~120cy visible work) that floored R6-R8.
// No pin can fix a >256-reg footprint. Fix: 8 waves x 32 cols per batch.
// Per-wave: bf 160->80, acc 48->16 (2 chains x 2 tc), total ~190 regs ->
// fits at 2 waves/SIMD (launch_bounds(512,2) -> 256 budget). MFMA pipe per
// SIMD unchanged (2x20=40/step); co-resident waves fill each other's
// latency stalls. NOT the R2 case: that halved VALU-bound fdot2 work on a
// shared VALU pipe with conflicted LDS traffic; h-reads here are
// conflict-free 4-chunk broadcasts (R7/R8: SQ_LDS_BANK_CONFLICT = 0).
__launch_bounds__(NTHR, 2)
__global__ void rnn_fused(const float* __restrict__ x,
                          const float* __restrict__ W_ih,
                          const float* __restrict__ W_hh,
                          const float* __restrict__ b_ih,
                          const float* __restrict__ b_hh,
                          const float* __restrict__ W_fc,
                          const float* __restrict__ b_fc,
                          float* __restrict__ out) {
    __shared__ __align__(16) __fp16 hlds[2][HH];  // 1 KB, double-buffered
    __shared__ float part[TT + 1][8];             // head partials, 65.6 KB

    const int tid  = threadIdx.x;
    const int b    = blockIdx.x;
    const int lane = tid & 63;
    const int w    = tid >> 6;     // wave 0..7: output cols [32w, 32w+32)
    const int g    = lane >> 4;    // 16-lane group 0..3 (k sub-slice)
    const int c16  = lane & 15;

    // ---- B fragments: bf[tc][T]: lane (g,c16) holds
    // W[n = 32w+16tc+c16][k = 32T + 8g + j], j=0..7  (T=8,9 -> W_ih, k-256)
    v8h bf[2][10];   // 80 VGPRs as 20 aligned quads
    v4f bvv[2];      // bias splat quads (C-init of chain A)
    float wf[2];
#pragma unroll
    for (int tc = 0; tc < 2; ++tc) {
        const int n = 32 * w + 16 * tc + c16;
#pragma unroll
        for (int T = 0; T < 8; ++T) {
            const float* wp = W_hh + n * HH + 32 * T + 8 * g;
            const float4 f0 = *(const float4*)wp;
            const float4 f1 = *(const float4*)(wp + 4);
            v4i r = {PK(f0.x, f0.y), PK(f0.z, f0.w), PK(f1.x, f1.y), PK(f1.z, f1.w)};
            bf[tc][T] = __builtin_bit_cast(v8h, r);
        }
#pragma unroll
        for (int T = 8; T < 10; ++T) {
            const float* wp = W_ih + n * II + 32 * (T - 8) + 8 * g;
            const float4 f0 = *(const float4*)wp;
            const float4 f1 = *(const float4*)(wp + 4);
            v4i r = {PK(f0.x, f0.y), PK(f0.z, f0.w), PK(f1.x, f1.y), PK(f1.z, f1.w)};
            bf[tc][T] = __builtin_bit_cast(v8h, r);
        }
        const float bias = b_ih[n] + b_hh[n];
        bvv[tc] = (v4f){bias, bias, bias, bias};
        wf[tc] = W_fc[n];
    }
    v4f zq = (v4f){0.f, 0.f, 0.f, 0.f};  // zero C-quad for chain B
    // pin as vectors (aligned quads, not rematerializable)
#pragma unroll
    for (int tc = 0; tc < 2; ++tc) {
#pragma unroll
        for (int T = 0; T < 10; ++T) asm volatile("" : "+v"(bf[tc][T]));
        asm volatile("" : "+v"(bvv[tc]));
        asm volatile("" : "+v"(wf[tc]));
    }
    asm volatile("" : "+v"(zq));
    const float bfc = b_fc[0];

    for (int idx = tid; idx < 2 * HH; idx += NTHR)
        ((__fp16*)hlds)[idx] = (__fp16)0;  // h_0 = 0
    __syncthreads();

    const float* xrow = x + (size_t)b * TT * II;
    float* outb = out + (size_t)b * TT;

    // h read base: GROUP-UNIFORM chunk address (broadcast within group);
    // k-tile T at byte offset T*64. Only lanes c16==0 feed D-row 0.
    const char* hrd0 = (const char*)&hlds[0][0] + g * 16;
    const char* hrd1 = (const char*)&hlds[1][0] + g * 16;
    // h write (lanes 0-15 only): col = 32w + 16tc + c16, tc -> +16 halves
    __fp16* hwr0 = &hlds[0][32 * w + c16];
    __fp16* hwr1 = &hlds[1][32 * w + c16];

    // x pipeline: xf8/xf9 = frags for step i; slots A/B raw rows i+1, i+2
    v8h xf8, xf9;
    float4 rA0, rA1, rA2, rA3, rB0, rB1, rB2, rB3;
    {
        const float* x0 = xrow;
        xf8 = xfrag(*(const float4*)(x0 + 8 * g), *(const float4*)(x0 + 8 * g + 4));
        xf9 = xfrag(*(const float4*)(x0 + 32 + 8 * g), *(const float4*)(x0 + 36 + 8 * g));
        const float* x1 = xrow + II;
        rA0 = *(const float4*)(x1 + 8 * g);      rA1 = *(const float4*)(x1 + 8 * g + 4);
        rA2 = *(const float4*)(x1 + 32 + 8 * g); rA3 = *(const float4*)(x1 + 36 + 8 * g);
        const float* x2 = xrow + 2 * II;
        rB0 = *(const float4*)(x2 + 8 * g);      rB1 = *(const float4*)(x2 + 8 * g + 4);
        rB2 = *(const float4*)(x2 + 32 + 8 * g); rB3 = *(const float4*)(x2 + 36 + 8 * g);
    }

    float ph = 0.0f;  // per-lane head partial of previous step (pre-reduce)

#define STEP(I, P, R0, R1, R2, R3)                                             \
    {                                                                          \
        /* issue all 8 h-tile reads (conflict-free b128 broadcast) */          \
        const char* hrd = (P) ? hrd1 : hrd0;                                   \
        const v8h hv0 = *(const v8h*)(hrd + 0 * 64);                           \
        const v8h hv1 = *(const v8h*)(hrd + 1 * 64);                           \
        const v8h hv2 = *(const v8h*)(hrd + 2 * 64);                           \
        const v8h hv3 = *(const v8h*)(hrd + 3 * 64);                           \
        const v8h hv4 = *(const v8h*)(hrd + 4 * 64);                           \
        const v8h hv5 = *(const v8h*)(hrd + 5 * 64);                           \
        const v8h hv6 = *(const v8h*)(hrd + 6 * 64);                           \
        const v8h hv7 = *(const v8h*)(hrd + 7 * 64);                           \
        /* deferred head of step I-1: 16-lane DPP reduce, fills read latency */\
        if ((I) > 0) {                                                         \
            float hc = ph;                                                     \
            hc = dpp_add<0xB1>(hc);                                            \
            hc = dpp_add<0x4E>(hc);                                            \
            hc = dpp_add<0x141>(hc);                                           \
            hc = dpp_add<0x140>(hc);                                           \
            if (lane == 0) part[I][w] = hc;                                    \
        }                                                                      \
        /* 20 MFMA, 2 chains x 2 tc (4 indep streams, dep distance 4) */       \
        v4f aA0 = MFMA(xf8, bf[0][8], bvv[0], 0, 0, 0);                        \
        v4f aA1 = MFMA(xf8, bf[1][8], bvv[1], 0, 0, 0);                        \
        v4f aB0 = MFMA(hv3, bf[0][3], zq, 0, 0, 0);                            \
        v4f aB1 = MFMA(hv3, bf[1][3], zq, 0, 0, 0);                            \
        aA0 = MFMA(xf9, bf[0][9], aA0, 0, 0, 0);                               \
        aA1 = MFMA(xf9, bf[1][9], aA1, 0, 0, 0);                               \
        aB0 = MFMA(hv4, bf[0][4], aB0, 0, 0, 0);                               \
        aB1 = MFMA(hv4, bf[1][4], aB1, 0, 0, 0);                               \
        aA0 = MFMA(hv0, bf[0][0], aA0, 0, 0, 0);                               \
        aA1 = MFMA(hv0, bf[1][0], aA1, 0, 0, 0);                               \
        aB0 = MFMA(hv5, bf[0][5], aB0, 0, 0, 0);                               \
        aB1 = MFMA(hv5, bf[1][5], aB1, 0, 0, 0);                               \
        aA0 = MFMA(hv1, bf[0][1], aA0, 0, 0, 0);                               \
        aA1 = MFMA(hv1, bf[1][1], aA1, 0, 0, 0);                               \
        aB0 = MFMA(hv6, bf[0][6], aB0, 0, 0, 0);                               \
        aB1 = MFMA(hv6, bf[1][6], aB1, 0, 0, 0);                               \
        aA0 = MFMA(hv2, bf[0][2], aA0, 0, 0, 0);                               \
        aA1 = MFMA(hv2, bf[1][2], aA1, 0, 0, 0);                               \
        aB0 = MFMA(hv7, bf[0][7], aB0, 0, 0, 0);                               \
        aB1 = MFMA(hv7, bf[1][7], aB1, 0, 0, 0);                               \
        /* x pipeline rotate: consume slot (row I+1), refill with row I+3 */   \
        xf8 = xfrag(R0, R1);                                                   \
        xf9 = xfrag(R2, R3);                                                   \
        {                                                                      \
            const int rn = ((I) + 3 < TT) ? ((I) + 3) : (TT - 1);              \
            const float* xp = xrow + rn * II;                                  \
            R0 = *(const float4*)(xp + 8 * g);                                 \
            R1 = *(const float4*)(xp + 8 * g + 4);                             \
            R2 = *(const float4*)(xp + 32 + 8 * g);                            \
            R3 = *(const float4*)(xp + 36 + 8 * g);                            \
        }                                                                      \
        /* tanh on D-row 0 (valid on lanes g==0; bounded garbage elsewhere) */ \
        const float h0 = ftanh(aA0[0] + aB0[0]);                               \
        const float h1 = ftanh(aA1[0] + aB1[0]);                               \
        ph = fmaf(h1, wf[1], h0 * wf[0]);                                      \
        if (lane < 16) {                                                       \
            __fp16* hp = (P) ? hwr0 : hwr1;                                    \
            hp[0]  = (__fp16)h0;                                               \
            hp[16] = (__fp16)h1;                                               \
        }                                                                      \
        /* LDS-only barrier: vmcnt NOT drained (x prefetch spans steps) */     \
        asm volatile("s_waitcnt lgkmcnt(0)\n\ts_barrier" ::: "memory");        \
    }

    for (int ib = 0; ib < TT; ib += 2) {
        STEP(ib, 0, rA0, rA1, rA2, rA3)
        STEP(ib + 1, 1, rB0, rB1, rB2, rB3)
    }
#undef STEP

    // final head (step TT-1) -> part[TT]
    {
        float hc = ph;
        hc = dpp_add<0xB1>(hc);
        hc = dpp_add<0x4E>(hc);
        hc = dpp_add<0x141>(hc);
        hc = dpp_add<0x140>(hc);
        if (lane == 0) part[TT][w] = hc;
    }
    __syncthreads();

    // ---- deferred output head: out[b][i] = sum(part[i+1][0..7]) + bfc ----
    for (int i = tid; i < TT; i += NTHR) {
        const float4 s0 = *(const float4*)&part[i + 1][0];
        const float4 s1 = *(const float4*)&part[i + 1][4];
        outb[i] = s0.x + s0.y + s0.z + s0.w + s1.x + s1.y + s1.z + s1.w + bfc;
    }
}

extern "C" void kernel_launch(void* const* d_in, const int* in_sizes, int n_in,
                              void* d_out, int out_size, void* d_ws, size_t ws_size,
                              hipStream_t stream) {
    const float* x    = (const float*)d_in[0];
    const float* W_ih = (const float*)d_in[1];
    const float* W_hh = (const float*)d_in[2];
    const float* b_ih = (const float*)d_in[3];
    const float* b_hh = (const float*)d_in[4];
    const float* W_fc = (const float*)d_in[5];
    const float* b_fc = (const float*)d_in[6];
    float* out = (float*)d_out;

    rnn_fused<<<BB, NTHR, 0, stream>>>(x, W_ih, W_hh, b_ih, b_hh, W_fc, b_fc, out);
}